// Round 8
// baseline (137.885 us; speedup 1.0000x reference)
//
#include <hip/hip_runtime.h>

#define IMG_H 512
#define IMG_W 512
#define NGAUSS 10000
#define N_VIEWS 4
#define PATCH 40

// -2 * ln(0.001): g > 0.001  <=>  q < QMAX (the -10 clip only shrinks g further)
#define QMAX 13.815511f

// Block = (view, row-class rc): owns the 8 STRIPED rows y = rc + 64*r.
// 4 views x 64 classes = 256 blocks = 1 per CU; 1024 threads = 16 waves/CU.
// Striping balances the Gaussian density peak across ALL blocks (R7's 4x
// hot-band imbalance was the stall). PATCH clamp => row-window height <= 40
// < 64, so each splat hits AT MOST ONE owned row -> single-list binning.
#define BLOCK_T 1024
#define NBLOCKS (N_VIEWS * 64)               // 256
#define QCAP 960                             // survivors/block ~670 avg
#define NBUCK 8                              // 64-col buckets per row
#define CAP_L 240                            // per-(row,bucket) list; hot ~170

__device__ __forceinline__ float fast_sigmoid(float x) {
    return 1.0f / (1.0f + __expf(-x));
}

// Single kernel, single graph node, NO workspace, NO atomics on image data.
// phase 1 (scan+prep fused): project all splats of the view; exact validity;
//   superset radius rub = sqrt(QMAX*exp(max ls)) + 0.5 (a,dd = sum R_ij^2 s_j
//   <= max s_j); window = AABB ∩ PATCH box ∩ image. If the window contains an
//   owned row, compute full params into LDS and append to that row's 1-2
//   64-col bucket lists.
// phase 2 (owner-computes eval): thread owns 4 px of one owned row; walks its
//   (row,bucket) list with next-entry prefetch; exact row reject
//   (min_dx q = dy^2*(i00*i11-i01^2)/i00 >= QMAX => g <= 0.001 whole row),
//   then evaluates the exact reference mask (g>0.001 ∧ PATCH box) per pixel,
//   accumulates in registers, stores 3 aligned float4 (each px written once).
__global__ __launch_bounds__(BLOCK_T) void gs_stripe_kernel(
    const float* __restrict__ poses,
    const float* __restrict__ Km,
    const float* __restrict__ means,
    const float* __restrict__ log_scales,
    const float* __restrict__ quats,
    const float* __restrict__ shs,
    const float* __restrict__ opac,
    float* __restrict__ out)
{
    __shared__ float4 s_p0[QCAP];                    // uvx uvy i00 i01 (15360 B)
    __shared__ float4 s_p1[QCAP];                    // i11 w0  w1  w2  (15360 B)
    __shared__ unsigned short s_list[8 * NBUCK][CAP_L];  //             (30720 B)
    __shared__ int s_ln[8 * NBUCK];
    __shared__ int s_qn;                             // total 61700 B < 64 KB

    const int view = blockIdx.x >> 6;
    const int rc   = blockIdx.x & 63;        // owned rows: rc + 64*r, r=0..7
    const int tid  = threadIdx.x;

    if (tid < 8 * NBUCK) s_ln[tid] = 0;
    if (tid == 0) s_qn = 0;
    __syncthreads();

    // wave-uniform camera constants (scalar loads)
    const float* P = poses + view * 16;
    const float P0 = P[0], P1 = P[1], P2  = P[2],  P3  = P[3];
    const float P4 = P[4], P5 = P[5], P6  = P[6],  P7  = P[7];
    const float P8 = P[8], P9 = P[9], P10 = P[10], P11 = P[11];
    const float K0 = Km[0], K1 = Km[1], K2 = Km[2];
    const float K3 = Km[3], K4 = Km[4], K5 = Km[5];
    const float K6 = Km[6], K7 = Km[7], K8 = Km[8];

    // ---- phase 1: scan all splats of this view; fused prep for survivors ----
    for (int n = tid; n < NGAUSS; n += BLOCK_T) {
        const float m0 = means[n * 3 + 0];
        const float m1 = means[n * 3 + 1];
        const float m2 = means[n * 3 + 2];

        const float Xc = P0 * m0 + P1 * m1 + P2  * m2 + P3;
        const float Yc = P4 * m0 + P5 * m1 + P6  * m2 + P7;
        const float Zc = P8 * m0 + P9 * m1 + P10 * m2 + P11;

        const float ppx = K0 * Xc + K1 * Yc + K2 * Zc;
        const float ppy = K3 * Xc + K4 * Yc + K5 * Zc;
        const float ppz = K6 * Xc + K7 * Yc + K8 * Zc;

        const float rcp = 1.0f / (ppz + 1e-8f);
        const float uvx = ppx * rcp;
        const float uvy = ppy * rcp;

        const int u = (int)uvx;   // trunc, matches jnp.trunc + int32 cast
        const int v = (int)uvy;

        if (!((Zc >= 0.1f) && (u >= 0) && (u < IMG_W) && (v >= 0) && (v < IMG_H)))
            continue;             // exact validity (same test as reference)

        // superset radius: a,dd <= exp(max log_scale)
        const float ls0 = log_scales[n * 3 + 0];
        const float ls1 = log_scales[n * 3 + 1];
        const float ls2 = log_scales[n * 3 + 2];
        const float rub = sqrtf(QMAX * __expf(fmaxf(fmaxf(ls0, ls1), ls2))) + 0.5f;

        const int ylo = max((int)ceilf (uvy - rub), max(v - PATCH / 2, 0));
        const int yhi = min((int)floorf(uvy + rub), min(v + PATCH / 2 - 1, IMG_H - 1));
        if (ylo > yhi) continue;

        // the single owned row (if any) this window touches: height <= 40 < 64
        const int r   = ((ylo - rc) + 63) >> 6;       // ceil((ylo-rc)/64), >= 0
        const int row = rc + (r << 6);
        if (row > yhi) continue;                      // also rejects r == 8

        const int xlo = max((int)ceilf (uvx - rub), max(u - PATCH / 2, 0));
        const int xhi = min((int)floorf(uvx + rub), min(u + PATCH / 2 - 1, IMG_W - 1));
        if (xlo > xhi) continue;

        // ---- survivor (~0.7/thread): full prep straight into LDS ----
        const float4 qv = *reinterpret_cast<const float4*>(quats + n * 4);
        const float qw = qv.x, qx = qv.y, qy = qv.z, qz = qv.w;
        const float R00 = 1.0f - 2.0f * (qy * qy + qz * qz);
        const float R01 = 2.0f * (qx * qy - qw * qz);
        const float R02 = 2.0f * (qx * qz + qw * qy);
        const float R10 = 2.0f * (qx * qy + qw * qz);
        const float R11 = 1.0f - 2.0f * (qx * qx + qz * qz);
        const float R12 = 2.0f * (qy * qz - qw * qx);

        const float s0 = __expf(ls0);
        const float s1 = __expf(ls1);
        const float s2 = __expf(ls2);

        const float a  = R00 * R00 * s0 + R01 * R01 * s1 + R02 * R02 * s2;
        const float b  = R00 * R10 * s0 + R01 * R11 * s1 + R02 * R12 * s2;
        const float dd = R10 * R10 * s0 + R11 * R11 * s1 + R12 * R12 * s2;

        const float det = a * dd - b * b;
        const float i00 =  dd / det;
        const float i01 = -b  / det;
        const float i11 =  a  / det;

        const float op = fast_sigmoid(opac[n]);
        const float w0 = op * fast_sigmoid(shs[n * 48 +  0]);
        const float w1 = op * fast_sigmoid(shs[n * 48 + 16]);
        const float w2 = op * fast_sigmoid(shs[n * 48 + 32]);

        const int qidx = atomicAdd(&s_qn, 1);
        if (qidx >= QCAP) continue;                   // overflow -> loud absmax fail
        s_p0[qidx] = make_float4(uvx, uvy, i00, i01);
        s_p1[qidx] = make_float4(i11, w0, w1, w2);

        const int b0 = xlo >> 6, b1 = xhi >> 6;       // 1-2 buckets (width <= 40)
        for (int bk = b0; bk <= b1; ++bk) {
            const int li = (r << 3) + bk;
            const int e  = atomicAdd(&s_ln[li], 1);
            if (e < CAP_L) s_list[li][e] = (unsigned short)qidx;
        }
    }
    __syncthreads();

    // ---- phase 2: owner-computes eval ----
    const int lr = tid >> 7;                 // local row index 0..7
    const int c0 = (tid & 127) << 2;         // owned cols c0..c0+3
    const int y  = rc + (lr << 6);           // owned image row
    const int li = (lr << 3) + (c0 >> 6);    // this thread's (row,bucket) list
    const float fy = (float)y;

    float accR[4] = {0.f, 0.f, 0.f, 0.f};
    float accG[4] = {0.f, 0.f, 0.f, 0.f};
    float accB[4] = {0.f, 0.f, 0.f, 0.f};

    const int ln = min(s_ln[li], CAP_L);
    unsigned short nq = (ln > 0) ? s_list[li][0] : (unsigned short)0;
    float4 np0 = s_p0[nq];
    float4 np1 = s_p1[nq];

    for (int k = 0; k < ln; ++k) {
        const float4 p0 = np0;
        const float4 p1 = np1;
        if (k + 1 < ln) {                    // prefetch next entry's params
            const unsigned short q2 = s_list[li][k + 1];
            np0 = s_p0[q2];
            np1 = s_p1[q2];
        }

        const float dy   = fy - p0.y;
        const float det2 = p0.z * p1.x - p0.w * p0.w;    // i00*i11 - i01^2 > 0
        // exact row reject: min over dx of q is dy^2*det2/i00
        if (dy * dy * det2 >= QMAX * p0.z) continue;

        const int   u  = (int)p0.x;
        const float c1 = 2.0f * p0.w * dy;
        const float c2 = p1.x * dy * dy;

        #pragma unroll
        for (int j = 0; j < 4; ++j) {
            const int col = c0 + j;
            const float dx = (float)col - p0.x;
            const float q  = (p0.z * dx + c1) * dx + c2;
            const float g  = __expf(fminf(fmaxf(-0.5f * q, -10.0f), 0.0f));
            // exact reference mask: g-threshold ∧ PATCH box (row part proven by binning)
            const bool ok = (g > 0.001f)
                          & (col >= u - PATCH / 2) & (col <= u + PATCH / 2 - 1);
            if (ok) {
                accR[j] += g * p1.y;
                accG[j] += g * p1.z;
                accB[j] += g * p1.w;
            }
        }
    }

    // ---- store owned pixels: 12 consecutive floats, 16B-aligned ----
    float4* o4 = reinterpret_cast<float4*>(
        out + (((size_t)view * IMG_H + y) * IMG_W + c0) * 3);
    o4[0] = make_float4(accR[0], accG[0], accB[0], accR[1]);
    o4[1] = make_float4(accG[1], accB[1], accR[2], accG[2]);
    o4[2] = make_float4(accB[2], accR[3], accG[3], accB[3]);
}

extern "C" void kernel_launch(void* const* d_in, const int* in_sizes, int n_in,
                              void* d_out, int out_size, void* d_ws, size_t ws_size,
                              hipStream_t stream) {
    const float* poses      = (const float*)d_in[0];
    const float* intrinsics = (const float*)d_in[1];
    const float* means      = (const float*)d_in[2];
    const float* log_scales = (const float*)d_in[3];
    const float* quats      = (const float*)d_in[4];
    const float* shs        = (const float*)d_in[5];
    const float* opac       = (const float*)d_in[6];
    float* out = (float*)d_out;

    // ONE kernel node, no workspace, no atomics on image data.
    gs_stripe_kernel<<<NBLOCKS, BLOCK_T, 0, stream>>>(
        poses, intrinsics, means, log_scales, quats, shs, opac, out);
}